// Round 6
// baseline (190.852 us; speedup 1.0000x reference)
//
#include <hip/hip_runtime.h>
#include <hip/hip_bf16.h>

// KANLayer: out = x @ Wb^T + silu(x) @ sum_g(Ws)^T
// One packed bf16 GEMM, K=2048: A'=[x|silu(x)], W'=[Wb|sum_g Ws], out=A'@W'^T.
// R14: m201 256^2 8-phase-class schedule via split-K=2.
//   R9/R10/R11 all pin at 37-41us = the documented m97-class ceiling (874-912
//   TF) -- barrier styling is a flat lever at 128-class tiles. R13 (B from
//   global) regressed 2x: lane-stride-4KB B loads = 16 lines/wave-load.
//   R12 (split-K) failed on 64B LDS rows (irreducible 4-way conflict), not
//   on split-K itself. This round: split-K=2 -> grid 256 of 256x256xK=1024
//   blocks, BK=64 (128B rows -> R9's PROVEN XOR swizzle on both A and B),
//   8 waves of 128x64, LDS 128KB = 2xA(32KB) + 2xB(32KB) slots.
//   Per K-tile: 4 phases x 16 MFMA (T3); stage A(s+1)@P0/P1, B(s+2)@P3
//   (B slot's last read is P2, barrier-protected) -> steady vmcnt(4) at
//   tile end, never 0 in main loop (T4). setprio around MFMA (T5),
//   XCD-paired ks blocks (T1). C pre-zeroed in prep; both halves
//   unsafeAtomicAdd (R12 proved correctness of this epilogue).

#define BATCH 8192
#define IN_F 1024
#define OUT_F 1024
#define KP 2048

typedef unsigned short ushort_t;
typedef __attribute__((ext_vector_type(8))) short short8;
typedef __attribute__((ext_vector_type(4))) float f32x4;

__device__ __forceinline__ ushort_t f2bf(float f) {
  union { float f; unsigned int u; } v;
  v.f = f;
  unsigned int u = v.u;
  u += 0x7fffu + ((u >> 16) & 1u);  // RNE
  return (ushort_t)(u >> 16);
}

// ---------------- merged prep (+ C zero for atomic accumulate) -----------
#define PREP_A_BLOCKS 4096
#define PREP_S_BLOCKS 1024
#define PREP_B_BLOCKS 1024
#define PREP_C_BLOCKS 2048
#define PREP_BLOCKS (PREP_A_BLOCKS + PREP_S_BLOCKS + PREP_B_BLOCKS + PREP_C_BLOCKS)

__global__ __launch_bounds__(256) void prep_all(
    const float* __restrict__ x, const float* __restrict__ Wb,
    const float* __restrict__ Ws, ushort_t* __restrict__ Apack,
    ushort_t* __restrict__ Wpack, float* __restrict__ Czero) {
  const int blk = blockIdx.x;
  const int t = threadIdx.x;

  if (blk < PREP_A_BLOCKS) {
    const int idx = blk * 256 + t;
    const int b = idx >> 7;
    const int i = (idx & 127) << 3;
    const float4 x0 = *(const float4*)(x + ((size_t)b << 10) + i);
    const float4 x1 = *(const float4*)(x + ((size_t)b << 10) + i + 4);
    float xv[8] = {x0.x, x0.y, x0.z, x0.w, x1.x, x1.y, x1.z, x1.w};
    ushort_t vb[8], vs[8];
#pragma unroll
    for (int j = 0; j < 8; ++j) {
      vb[j] = f2bf(xv[j]);
      vs[j] = f2bf(xv[j] / (1.0f + __expf(-xv[j])));
    }
    ushort_t* row = Apack + ((size_t)b << 11);
    *(short8*)(row + i) = *(short8*)vb;
    *(short8*)(row + IN_F + i) = *(short8*)vs;
  } else if (blk < PREP_A_BLOCKS + PREP_S_BLOCKS) {
    const int idx = (blk - PREP_A_BLOCKS) * 256 + t;
    const int o = idx >> 8;
    const int i0 = (idx & 255) << 2;
    ushort_t vs[4];
#pragma unroll
    for (int j = 0; j < 4; ++j) {
      const float4* p = (const float4*)(Ws + ((((size_t)o << 10) + i0 + j) << 3));
      const float4 a = p[0];
      const float4 b = p[1];
      vs[j] = f2bf(((a.x + a.y) + (a.z + a.w)) + ((b.x + b.y) + (b.z + b.w)));
    }
    *(ushort4*)(Wpack + ((size_t)o << 11) + IN_F + i0) = *(ushort4*)vs;
  } else if (blk < PREP_A_BLOCKS + PREP_S_BLOCKS + PREP_B_BLOCKS) {
    const int idx = (blk - PREP_A_BLOCKS - PREP_S_BLOCKS) * 256 + t;
    const int o = idx >> 8;
    const int c = (idx & 255) << 2;
    const float4 w = *(const float4*)(Wb + ((size_t)o << 10) + c);
    ushort4 v;
    v.x = f2bf(w.x); v.y = f2bf(w.y); v.z = f2bf(w.z); v.w = f2bf(w.w);
    *(ushort4*)(Wpack + ((size_t)o << 11) + c) = v;
  } else {
    const int idx = blk - (PREP_A_BLOCKS + PREP_S_BLOCKS + PREP_B_BLOCKS);
    float4* p = (float4*)Czero + (((size_t)(idx * 256 + t)) << 2);
    const float4 z = make_float4(0.f, 0.f, 0.f, 0.f);
    p[0] = z; p[1] = z; p[2] = z; p[3] = z;
  }
}

// ---------------- GEMM (split-K=2, 256x256 tiles, m201 schedule) ----------
#define BM 256
#define BN 256
#define KHALF 1024
#define GBK 64
#define NTILE (KHALF / GBK)   // 16 K-tiles
#define A_SLOT 16384          // ushorts per slot: 256 rows x 64 = 32 KB
#define LDS_B0 32768          // ushort offset of B slots

typedef const __attribute__((address_space(1))) unsigned int gas_uint;
typedef __attribute__((address_space(3))) unsigned int las_uint;
#define ASYNC16(l, g) \
  __builtin_amdgcn_global_load_lds((gas_uint*)(g), (las_uint*)(l), 16, 0, 0)

#define LGKM0() do { \
  asm volatile("s_waitcnt lgkmcnt(0)" ::: "memory"); \
  __builtin_amdgcn_sched_barrier(0); \
} while (0)

#define MFMA16(MB, BF)                                                       \
  do {                                                                       \
    __builtin_amdgcn_s_setprio(1);                                           \
    _Pragma("unroll") for (int mi = 0; mi < 4; ++mi)                         \
        _Pragma("unroll") for (int ni = 0; ni < 4; ++ni)                     \
            acc[(MB) + mi][ni] = __builtin_amdgcn_mfma_f32_16x16x32_bf16(    \
                af[mi], BF[ni], acc[(MB) + mi][ni], 0, 0, 0);                \
    __builtin_amdgcn_s_setprio(0);                                           \
  } while (0)

__global__ __launch_bounds__(512, 2) void gemm_splitk(
    const ushort_t* __restrict__ A,  // [BATCH][KP]
    const ushort_t* __restrict__ W,  // [OUT_F][KP]
    float* __restrict__ C) {         // [BATCH][OUT_F], pre-zeroed
  __shared__ __align__(16) ushort_t lds[65536];  // 128 KB: A0 A1 B0 B1

  const int t = threadIdx.x;
  const int flat = blockIdx.x;            // 0..255
  const int xcd = flat & 7;
  const int ks = flat >> 7;               // K-half 0/1 (pair flat^128: same xcd)
  const int tile = xcd * 16 + ((flat >> 3) & 15);  // 0..127, XCD-local slabs
  const int mt = tile >> 2;               // 0..31
  const int nt = tile & 3;                // 0..3

  const int lane = t & 63;
  const int wave = t >> 6;  // 0..7
  const int wr = wave >> 2; // 0..1 (M half, 128 rows)
  const int wc = wave & 3;  // 0..3 (N quarter, 64 cols)
  const int lr = lane & 15;
  const int lq = lane >> 4;

  // ---- staging (R9-proven pattern): thread t -> row r=t>>3 (+64k), 16B
  //      chunk kc=(t&7)^(r&7). (r+64k)&7 == r&7, so one kc serves all 4 rows.
  const int r = t >> 3;                  // 0..63
  const int kc = (t & 7) ^ (r & 7);
  const ushort_t* ga = A + (size_t)(mt * BM + r) * KP + ks * KHALF + kc * 8;
  const ushort_t* gb = W + (size_t)(nt * BN + r) * KP + ks * KHALF + kc * 8;
  const size_t rskip = (size_t)64 * KP;
  ushort_t* const ld0 = lds + t * 8;     // linear 16B/thread dest base

  // ---- fragment read offsets (R9-proven granule math, 0 conflicts) ----
  int aoff[2][8], boff[2][4];
#pragma unroll
  for (int kk = 0; kk < 2; ++kk) {
#pragma unroll
    for (int mi = 0; mi < 8; ++mi) {
      const int arow = wr * 128 + mi * 16 + lr;
      aoff[kk][mi] = arow * 64 + (((kk * 4 + lq) ^ (arow & 7)) << 3);
    }
#pragma unroll
    for (int ni = 0; ni < 4; ++ni) {
      const int brow = wc * 64 + ni * 16 + lr;
      boff[kk][ni] = brow * 64 + (((kk * 4 + lq) ^ (brow & 7)) << 3);
    }
  }

  f32x4 acc[8][4];
#pragma unroll
  for (int mi = 0; mi < 8; ++mi)
#pragma unroll
    for (int ni = 0; ni < 4; ++ni) acc[mi][ni] = (f32x4){0.f, 0.f, 0.f, 0.f};

#define STAGE4(dofs, g) do { \
    ASYNC16(ld0 + (dofs), (g)); \
    ASYNC16(ld0 + (dofs) + 4096, (g) + rskip); \
    ASYNC16(ld0 + (dofs) + 8192, (g) + 2 * rskip); \
    ASYNC16(ld0 + (dofs) + 12288, (g) + 3 * rskip); \
  } while (0)

  // ---- prologue: A(0),B(0),A(1),B(1) = 16 loads; drain first 8 ----
  STAGE4(0, ga);
  STAGE4(LDS_B0, gb);
  STAGE4(A_SLOT, ga + GBK);
  STAGE4(LDS_B0 + A_SLOT, gb + GBK);
  asm volatile("s_waitcnt vmcnt(8)" ::: "memory");
  __builtin_amdgcn_s_barrier();
  __builtin_amdgcn_sched_barrier(0);

  // One K-tile: 4 phases x 16 MFMA. SA: stage A(s+1) (P0/P1, 2+2 loads);
  // SB: stage B(s+2) (P3, 4 loads; its slot's last read is P2). VM: end wait.
#define TILE(la, lb, SA, ga_next, a_dofs, SB, gb_next2, b_dofs, VMSTR, ENDBAR) \
  do {                                                                        \
    short8 af[4], bf0[4], bf1[4];                                             \
    /* P0: A m0-3 kk0 + B kk0 | stage A(s+1) half0 */                         \
    _Pragma("unroll") for (int i = 0; i < 4; ++i)                             \
        af[i] = *(const short8*)((la) + aoff[0][i]);                          \
    _Pragma("unroll") for (int i = 0; i < 4; ++i)                             \
        bf0[i] = *(const short8*)((lb) + boff[0][i]);                         \
    if (SA) { ASYNC16(ld0 + (a_dofs), (ga_next));                             \
              ASYNC16(ld0 + (a_dofs) + 4096, (ga_next) + rskip); }            \
    __builtin_amdgcn_s_barrier();                                             \
    LGKM0();                                                                  \
    MFMA16(0, bf0);                                                           \
    __builtin_amdgcn_s_barrier();                                             \
    /* P1: A m4-7 kk0 (B in regs) | stage A(s+1) half1 */                     \
    _Pragma("unroll") for (int i = 0; i < 4; ++i)                             \
        af[i] = *(const short8*)((la) + aoff[0][4 + i]);                      \
    if (SA) { ASYNC16(ld0 + (a_dofs) + 8192, (ga_next) + 2 * rskip);          \
              ASYNC16(ld0 + (a_dofs) + 12288, (ga_next) + 3 * rskip); }       \
    __builtin_amdgcn_s_barrier();                                             \
    LGKM0();                                                                  \
    MFMA16(4, bf0);                                                           \
    __builtin_amdgcn_s_barrier();                                             \
    /* P2: A m0-3 kk1 + B kk1 (last read of this B slot) */                   \
    _Pragma("unroll") for (int i = 0; i < 4; ++i)                             \
        af[i] = *(const short8*)((la) + aoff[1][i]);                          \
    _Pragma("unroll") for (int i = 0; i < 4; ++i)                             \
        bf1[i] = *(const short8*)((lb) + boff[1][i]);                         \
    __builtin_amdgcn_s_barrier();                                             \
    LGKM0();                                                                  \
    MFMA16(0, bf1);                                                           \
    __builtin_amdgcn_s_barrier();                                             \
    /* P3: A m4-7 kk1 | stage B(s+2) into this B slot (freed after P2) */     \
    _Pragma("unroll") for (int i = 0; i < 4; ++i)                             \
        af[i] = *(const short8*)((la) + aoff[1][4 + i]);                      \
    if (SB) STAGE4((b_dofs), (gb_next2));                                     \
    __builtin_amdgcn_s_barrier();                                             \
    LGKM0();                                                                  \
    MFMA16(4, bf1);                                                           \
    if (ENDBAR) {                                                             \
      asm volatile(VMSTR ::: "memory");                                       \
      __builtin_amdgcn_s_barrier();                                           \
      __builtin_amdgcn_sched_barrier(0);                                      \
    }                                                                         \
  } while (0)

  // ---- tile 0: stage B(2) only; end vmcnt(4) leaves B(2) in flight ----
  TILE(lds, lds + LDS_B0, false, ga, 0, true, gb + 2 * GBK, LDS_B0,
       "s_waitcnt vmcnt(4)", true);

  // ---- tiles 1..13 (steady): stage A(s+1), B(s+2); vmcnt(4) ----
  {
    const ushort_t* gsa = ga + 2 * GBK;  // A(s+1) source at s=1
    const ushort_t* gsb = gb + 3 * GBK;  // B(s+2) source at s=1
#pragma unroll 1
    for (int s = 1; s <= 13; ++s) {
      const int cur = s & 1;
      const ushort_t* la = lds + cur * A_SLOT;
      const ushort_t* lb = lds + LDS_B0 + cur * A_SLOT;
      const int a_dofs = (cur ^ 1) * A_SLOT;          // A slot (s+1)&1
      const int b_dofs = LDS_B0 + cur * A_SLOT;       // B slot s&1 (= (s+2)&1)
      TILE(la, lb, true, gsa, a_dofs, true, gsb, b_dofs,
           "s_waitcnt vmcnt(4)", true);
      gsa += GBK;
      gsb += GBK;
    }
  }

  // ---- tile 14: stage A(15) only; full drain vmcnt(0) ----
  TILE(lds, lds + LDS_B0, true, ga + 15 * GBK, A_SLOT, false, gb, 0,
       "s_waitcnt vmcnt(0)", true);
  // ---- tile 15: pure compute, no end barrier ----
  TILE(lds + A_SLOT, lds + LDS_B0 + A_SLOT, false, ga, 0, false, gb, 0,
       "s_nop 0", false);

  // ---- epilogue: atomic accumulate (C pre-zeroed; the 2 ks halves add).
  // C/D layout: col = lane&15, row = (lane>>4)*4 + reg (m89-verified).
  const int col0 = nt * BN + wc * 64 + lr;
  const int row0 = mt * BM + wr * 128 + (lq << 2);
#pragma unroll
  for (int mi = 0; mi < 8; ++mi)
#pragma unroll
    for (int ni = 0; ni < 4; ++ni) {
      float* cp = C + (size_t)(row0 + mi * 16) * OUT_F + col0 + ni * 16;
#pragma unroll
      for (int rr = 0; rr < 4; ++rr)
        unsafeAtomicAdd(cp + (size_t)rr * OUT_F, acc[mi][ni][rr]);
    }
}

extern "C" void kernel_launch(void* const* d_in, const int* in_sizes, int n_in,
                              void* d_out, int out_size, void* d_ws, size_t ws_size,
                              hipStream_t stream) {
  const float* x = (const float*)d_in[0];
  const float* wb = (const float*)d_in[1];
  const float* ws = (const float*)d_in[2];
  float* out = (float*)d_out;

  ushort_t* Apack = (ushort_t*)d_ws;                                    // 33.5 MB
  ushort_t* Wpack = (ushort_t*)((char*)d_ws + (size_t)BATCH * KP * 2);  // +4 MB

  prep_all<<<PREP_BLOCKS, 256, 0, stream>>>(x, wb, ws, Apack, Wpack, out);
  gemm_splitk<<<dim3(256), dim3(512), 0, stream>>>(Apack, Wpack, out);
}

// Round 7
// 149.357 us; speedup vs baseline: 1.2778x; 1.2778x over previous
//
#include <hip/hip_runtime.h>
#include <hip/hip_bf16.h>

// KANLayer: out = x @ Wb^T + silu(x) @ sum_g(Ws)^T
// One packed bf16 GEMM, K=2048: A'=[x|silu(x)], W'=[Wb|sum_g Ws], out=A'@W'^T.
// R15: B-in-registers from FRAGMENT-TILED Wpack + 2 blocks/CU.
//   Serial-phase model (fits R9..R14 + m201): phase = LDS-drain + MFMA + bar,
//   strictly serial within a block -> the levers are LDS-bytes/MFMA and
//   multiple ASYNC blocks/CU (m114 pipe co-scheduling). R13's B-from-global
//   failed only because row-major W made frag loads stride-4KB scatters;
//   prep now writes Wpack tiled [n/16][k/8][16][8] so one wave B-frag load
//   = 1024 CONTIGUOUS bytes (fast class), L2-resident (4MB, 64x reuse),
//   prefetched 1 step ahead into named dbuf regs (b0/b1).
//   A stays in LDS: byte-identical R9 swizzle (BK=64, 128B rows, measured
//   0 conflicts), ring-3, counted vmcnt(4) (T4; issue order pinned).
//   Geometry: BM=BN=128, 256thr = 4 waves of 64x64, grid 512 = 2 blocks/CU
//   (48KB LDS/block). Per CU/step: LDS 96KB (~860cy), MFMA 1240cy, B-VMEM
//   ~1100cy from L2 -- three pipes overlapped by two async blocks.
//   T1 XCD map, T5 setprio retained. Direct C store (no atomics).

#define BATCH 8192
#define IN_F 1024
#define OUT_F 1024
#define KP 2048

typedef unsigned short ushort_t;
typedef __attribute__((ext_vector_type(8))) short short8;
typedef __attribute__((ext_vector_type(4))) float f32x4;

__device__ __forceinline__ ushort_t f2bf(float f) {
  union { float f; unsigned int u; } v;
  v.f = f;
  unsigned int u = v.u;
  u += 0x7fffu + ((u >> 16) & 1u);  // RNE
  return (ushort_t)(u >> 16);
}

// Tiled Wpack addressing: ushort index of (row o, col k) =
//   ((o>>4)*256 + (k>>3))*128 + (o&15)*8 + (k&7)
// -> a 16-row x 8-col fragment block is 256 contiguous bytes.
__device__ __forceinline__ size_t wtile_idx(int o, int k) {
  return (((size_t)(o >> 4) * 256 + (k >> 3)) << 7) + ((o & 15) << 3) + (k & 7);
}

// ---------------- merged prep -----------
#define PREP_A_BLOCKS 4096
#define PREP_S_BLOCKS 1024
#define PREP_B_BLOCKS 1024
#define PREP_BLOCKS (PREP_A_BLOCKS + PREP_S_BLOCKS + PREP_B_BLOCKS)

__global__ __launch_bounds__(256) void prep_all(
    const float* __restrict__ x, const float* __restrict__ Wb,
    const float* __restrict__ Ws, ushort_t* __restrict__ Apack,
    ushort_t* __restrict__ Wpack) {
  const int blk = blockIdx.x;
  const int t = threadIdx.x;

  if (blk < PREP_A_BLOCKS) {
    const int idx = blk * 256 + t;
    const int b = idx >> 7;
    const int i = (idx & 127) << 3;
    const float4 x0 = *(const float4*)(x + ((size_t)b << 10) + i);
    const float4 x1 = *(const float4*)(x + ((size_t)b << 10) + i + 4);
    float xv[8] = {x0.x, x0.y, x0.z, x0.w, x1.x, x1.y, x1.z, x1.w};
    ushort_t vb[8], vs[8];
#pragma unroll
    for (int j = 0; j < 8; ++j) {
      vb[j] = f2bf(xv[j]);
      vs[j] = f2bf(xv[j] / (1.0f + __expf(-xv[j])));
    }
    ushort_t* row = Apack + ((size_t)b << 11);
    *(short8*)(row + i) = *(short8*)vb;
    *(short8*)(row + IN_F + i) = *(short8*)vs;
  } else if (blk < PREP_A_BLOCKS + PREP_S_BLOCKS) {
    // spline weights -> W' columns IN_F..2047 (tiled layout)
    const int idx = (blk - PREP_A_BLOCKS) * 256 + t;
    const int o = idx >> 8;
    const int i0 = (idx & 255) << 2;
    ushort_t vs[4];
#pragma unroll
    for (int j = 0; j < 4; ++j) {
      const float4* p = (const float4*)(Ws + ((((size_t)o << 10) + i0 + j) << 3));
      const float4 a = p[0];
      const float4 b = p[1];
      vs[j] = f2bf(((a.x + a.y) + (a.z + a.w)) + ((b.x + b.y) + (b.z + b.w)));
    }
    // k0 = IN_F + i0 is a multiple of 4 -> 4 ushorts stay inside one 8-chunk
    *(ushort4*)(Wpack + wtile_idx(o, IN_F + i0)) = *(ushort4*)vs;
  } else {
    // base weights -> W' columns 0..1023 (tiled layout)
    const int idx = (blk - PREP_A_BLOCKS - PREP_S_BLOCKS) * 256 + t;
    const int o = idx >> 8;
    const int c = (idx & 255) << 2;
    const float4 w = *(const float4*)(Wb + ((size_t)o << 10) + c);
    ushort4 v;
    v.x = f2bf(w.x); v.y = f2bf(w.y); v.z = f2bf(w.z); v.w = f2bf(w.w);
    *(ushort4*)(Wpack + wtile_idx(o, c)) = v;
  }
}

// ---------------- GEMM ----------------
#define BM 128
#define BN 128
#define GBK 64
#define NSTEP (KP / GBK)   // 32
#define A_SLOT 8192        // ushorts: 128 rows x 64 = 16 KB
#define NSLOT 3            // 48 KB A-ring

typedef const __attribute__((address_space(1))) unsigned int gas_uint;
typedef __attribute__((address_space(3))) unsigned int las_uint;
#define ASYNC16(l, g) \
  __builtin_amdgcn_global_load_lds((gas_uint*)(g), (las_uint*)(l), 16, 0, 0)

#define SBAR0() __builtin_amdgcn_sched_barrier(0)

__global__ __launch_bounds__(256, 2) void gemm_packed(
    const ushort_t* __restrict__ A,  // [BATCH][KP]
    const ushort_t* __restrict__ W,  // tiled Wpack
    float* __restrict__ C) {         // [BATCH][OUT_F]
  __shared__ __align__(16) ushort_t lds[NSLOT * A_SLOT];  // 48 KB, A only

  const int t = threadIdx.x;
  const int flat = blockIdx.x;           // 0..511
  const int xcd = flat & 7;
  const int local = flat >> 3;           // 0..63
  const int nt = local >> 3;             // 0..7
  const int mt = xcd * 8 + (local & 7);  // 0..63 (XCD-local A slabs)

  const int lane = t & 63;
  const int wave = t >> 6;  // 0..3
  const int wr = wave >> 1; // 0..1 (M half)
  const int wc = wave & 1;  // 0..1 (N half)
  const int lr = lane & 15;
  const int lq = lane >> 4;

  // ---- A staging (R9-proven pattern): thread t -> row r = t>>3 (0..31,
  //      4 rounds of +32), phys chunk t&7; fetched global k-chunk =
  //      (t&7)^(r&7). (r+32j)&7 == r&7, so one kc serves all rounds.
  const int r = t >> 3;
  const int kc = (t & 7) ^ (r & 7);
  const ushort_t* ga = A + (size_t)(mt * BM + r) * KP + kc * 8;
  const size_t rskip = (size_t)32 * KP;
  const int ldst = t * 8;                // 16B/thread; rounds at +2048 ushorts

  // ---- A fragment read offsets (R9-proven, 0 conflicts) ----
  int aoff[2][4];
#pragma unroll
  for (int kk = 0; kk < 2; ++kk)
#pragma unroll
    for (int i = 0; i < 4; ++i) {
      const int arow = wr * 64 + i * 16 + lr;
      aoff[kk][i] = arow * 64 + (((kk * 4 + lq) ^ (arow & 7)) << 3);
    }

  // ---- B fragment global pointers (tiled Wpack): frag j = (kk=j>>2, ni=j&3)
  //      one wave load = 4 consecutive 256B blocks = 1024B contiguous.
  const ushort_t* bp[8];
#pragma unroll
  for (int j = 0; j < 8; ++j) {
    const int ni = j & 3;
    const int kk = j >> 2;
    const int g = nt * 8 + wc * 4 + ni;         // 16-row group index
    bp[j] = W + (((size_t)g * 256 + kk * 4 + lq) << 7) + (lr << 3);
  }

  f32x4 acc[4][4];
#pragma unroll
  for (int mi = 0; mi < 4; ++mi)
#pragma unroll
    for (int ni = 0; ni < 4; ++ni) acc[mi][ni] = (f32x4){0.f, 0.f, 0.f, 0.f};

  short8 b0[8], b1[8];
  int co = 0;                 // compute slot offset (s % 3)
  int so = 2 * A_SLOT;        // stage slot offset ((s+2) % 3)
  const ushort_t* gsa = ga + 2 * GBK;  // A(s+2) source
  int gk = 1024;              // B(s+1) ushort offset (tiled: 1024/step)

#define STAGE_A4() do { \
    ushort_t* sa = lds + so + ldst; \
    ASYNC16(sa, gsa); \
    ASYNC16(sa + 2048, gsa + rskip); \
    ASYNC16(sa + 4096, gsa + 2 * rskip); \
    ASYNC16(sa + 6144, gsa + 3 * rskip); \
    gsa += GBK; \
  } while (0)

#define MFMA16(BF, H)                                                        \
  do {                                                                       \
    __builtin_amdgcn_s_setprio(1);                                           \
    _Pragma("unroll") for (int mi = 0; mi < 4; ++mi)                         \
        _Pragma("unroll") for (int ni = 0; ni < 4; ++ni)                     \
            acc[mi][ni] = __builtin_amdgcn_mfma_f32_16x16x32_bf16(           \
                af[mi], BF[(H) + ni], acc[mi][ni], 0, 0, 0);                 \
    __builtin_amdgcn_s_setprio(0);                                           \
  } while (0)

// One K=64 step: compute slot co x BC; prefetch B(s+1)->BNX (issued before
// the A-stage so end-of-step vmcnt(4) leaves exactly A(s+2) in flight).
#define GEMM_STEP(BC, BNX, PF, ST)                                           \
  do {                                                                       \
    const ushort_t* ab = lds + co;                                           \
    short8 af[4];                                                            \
    _Pragma("unroll") for (int i = 0; i < 4; ++i)                            \
        af[i] = *(const short8*)(ab + aoff[0][i]);                           \
    if (PF) {                                                                \
      _Pragma("unroll") for (int j = 0; j < 4; ++j)                          \
          BNX[j] = *(const short8*)(bp[j] + gk);                             \
    }                                                                        \
    SBAR0();                                                                 \
    MFMA16(BC, 0);                                                           \
    _Pragma("unroll") for (int i = 0; i < 4; ++i)                            \
        af[i] = *(const short8*)(ab + aoff[1][i]);                           \
    if (PF) {                                                                \
      _Pragma("unroll") for (int j = 4; j < 8; ++j)                          \
          BNX[j] = *(const short8*)(bp[j] + gk);                             \
      gk += 1024;                                                            \
    }                                                                        \
    SBAR0();                                                                 \
    if (ST) STAGE_A4();                                                      \
    SBAR0();                                                                 \
    MFMA16(BC, 4);                                                           \
  } while (0)

#define ENDSTEP(VMC)                                                         \
  do {                                                                       \
    asm volatile("s_waitcnt vmcnt(" #VMC ")" ::: "memory");                  \
    __builtin_amdgcn_s_barrier();                                            \
    SBAR0();                                                                 \
    co += A_SLOT; if (co == NSLOT * A_SLOT) co = 0;                          \
    so += A_SLOT; if (so == NSLOT * A_SLOT) so = 0;                          \
  } while (0)

  // ---- prologue: A(0) x4, B(0) x8, A(1) x4 -> vmcnt(4) leaves A(1) ----
  {
    ushort_t* sa0 = lds + ldst;
    ASYNC16(sa0, ga);
    ASYNC16(sa0 + 2048, ga + rskip);
    ASYNC16(sa0 + 4096, ga + 2 * rskip);
    ASYNC16(sa0 + 6144, ga + 3 * rskip);
    SBAR0();
#pragma unroll
    for (int j = 0; j < 8; ++j) b0[j] = *(const short8*)(bp[j]);
    SBAR0();
    ushort_t* sa1 = lds + A_SLOT + ldst;
    ASYNC16(sa1, ga + GBK);
    ASYNC16(sa1 + 2048, ga + GBK + rskip);
    ASYNC16(sa1 + 4096, ga + GBK + 2 * rskip);
    ASYNC16(sa1 + 6144, ga + GBK + 3 * rskip);
  }
  asm volatile("s_waitcnt vmcnt(4)" ::: "memory");
  __builtin_amdgcn_s_barrier();
  SBAR0();

  // ---- main loop: steps 0..29 as 15 double-steps ----
#pragma unroll 1
  for (int s2 = 0; s2 < (NSTEP - 2) / 2; ++s2) {
    GEMM_STEP(b0, b1, true, true);
    ENDSTEP(4);
    GEMM_STEP(b1, b0, true, true);
    ENDSTEP(4);
  }
  // ---- tail: step 30 (prefetch B31, no stage; full drain), step 31 ----
  GEMM_STEP(b0, b1, true, false);
  ENDSTEP(0);
  GEMM_STEP(b1, b0, false, false);

  // ---- epilogue: C/D layout col=lane&15, row=(lane>>4)*4+reg ----
  const int col0 = nt * BN + wc * 64 + lr;
  const int row0 = mt * BM + wr * 64 + (lq << 2);
#pragma unroll
  for (int mi = 0; mi < 4; ++mi)
#pragma unroll
    for (int ni = 0; ni < 4; ++ni) {
      float* cp = C + (size_t)(row0 + mi * 16) * OUT_F + col0 + ni * 16;
#pragma unroll
      for (int rr = 0; rr < 4; ++rr) cp[(size_t)rr * OUT_F] = acc[mi][ni][rr];
    }
}

extern "C" void kernel_launch(void* const* d_in, const int* in_sizes, int n_in,
                              void* d_out, int out_size, void* d_ws, size_t ws_size,
                              hipStream_t stream) {
  const float* x = (const float*)d_in[0];
  const float* wb = (const float*)d_in[1];
  const float* ws = (const float*)d_in[2];
  float* out = (float*)d_out;

  ushort_t* Apack = (ushort_t*)d_ws;                                    // 33.5 MB
  ushort_t* Wpack = (ushort_t*)((char*)d_ws + (size_t)BATCH * KP * 2);  // +4 MB

  prep_all<<<PREP_BLOCKS, 256, 0, stream>>>(x, wb, ws, Apack, Wpack);
  gemm_packed<<<dim3((BATCH / BM) * (OUT_F / BN)), dim3(256), 0, stream>>>(Apack, Wpack, out);
}

// Round 10
// 143.079 us; speedup vs baseline: 1.3339x; 1.0439x over previous
//
#include <hip/hip_runtime.h>
#include <hip/hip_bf16.h>

// KANLayer: out = x @ Wb^T + silu(x) @ sum_g(Ws)^T
// One packed bf16 GEMM, K=2048: A'=[x|silu(x)], W'=[Wb|sum_g Ws], out=A'@W'^T.
// R18 = exact revert to R10 (session best, 140.76us total; gemm ~38us).
// 4 phases x 8 MFMA per K-step, 3-deep LDS ring, counted vmcnt(6),
// both-sides XOR swizzle (0 conflicts measured), XCD-swizzled blocks,
// setprio around MFMA clusters.

#define BATCH 8192
#define IN_F 1024
#define OUT_F 1024
#define KP 2048

typedef unsigned short ushort_t;
typedef __attribute__((ext_vector_type(8))) short short8;
typedef __attribute__((ext_vector_type(4))) float f32x4;

__device__ __forceinline__ ushort_t f2bf(float f) {
  union { float f; unsigned int u; } v;
  v.f = f;
  unsigned int u = v.u;
  u += 0x7fffu + ((u >> 16) & 1u);  // RNE
  return (ushort_t)(u >> 16);
}

// ---------------- merged prep (~traffic floor) -----------
#define PREP_A_BLOCKS 4096
#define PREP_S_BLOCKS 1024
#define PREP_B_BLOCKS 1024
#define PREP_BLOCKS (PREP_A_BLOCKS + PREP_S_BLOCKS + PREP_B_BLOCKS)

__global__ __launch_bounds__(256) void prep_all(
    const float* __restrict__ x, const float* __restrict__ Wb,
    const float* __restrict__ Ws, ushort_t* __restrict__ Apack,
    ushort_t* __restrict__ Wpack) {
  const int blk = blockIdx.x;
  const int t = threadIdx.x;

  if (blk < PREP_A_BLOCKS) {
    const int idx = blk * 256 + t;
    const int b = idx >> 7;
    const int i = (idx & 127) << 3;
    const float4 x0 = *(const float4*)(x + ((size_t)b << 10) + i);
    const float4 x1 = *(const float4*)(x + ((size_t)b << 10) + i + 4);
    float xv[8] = {x0.x, x0.y, x0.z, x0.w, x1.x, x1.y, x1.z, x1.w};
    ushort_t vb[8], vs[8];
#pragma unroll
    for (int j = 0; j < 8; ++j) {
      vb[j] = f2bf(xv[j]);
      vs[j] = f2bf(xv[j] / (1.0f + __expf(-xv[j])));
    }
    ushort_t* row = Apack + ((size_t)b << 11);
    *(short8*)(row + i) = *(short8*)vb;
    *(short8*)(row + IN_F + i) = *(short8*)vs;
  } else if (blk < PREP_A_BLOCKS + PREP_S_BLOCKS) {
    const int idx = (blk - PREP_A_BLOCKS) * 256 + t;
    const int o = idx >> 8;
    const int i0 = (idx & 255) << 2;
    ushort_t vs[4];
#pragma unroll
    for (int j = 0; j < 4; ++j) {
      const float4* p = (const float4*)(Ws + ((((size_t)o << 10) + i0 + j) << 3));
      const float4 a = p[0];
      const float4 b = p[1];
      vs[j] = f2bf(((a.x + a.y) + (a.z + a.w)) + ((b.x + b.y) + (b.z + b.w)));
    }
    *(ushort4*)(Wpack + ((size_t)o << 11) + IN_F + i0) = *(ushort4*)vs;
  } else {
    const int idx = (blk - PREP_A_BLOCKS - PREP_S_BLOCKS) * 256 + t;
    const int o = idx >> 8;
    const int c = (idx & 255) << 2;
    const float4 w = *(const float4*)(Wb + ((size_t)o << 10) + c);
    ushort4 v;
    v.x = f2bf(w.x); v.y = f2bf(w.y); v.z = f2bf(w.z); v.w = f2bf(w.w);
    *(ushort4*)(Wpack + ((size_t)o << 11) + c) = v;
  }
}

// ---------------- GEMM ----------------
#define BM 256
#define BN 128
#define GBK 64
#define NSTEP (KP / GBK)       // 32
#define A_US 16384             // A region: 256 rows x 64 ushorts = 32 KB
#define B_US 8192              // B region: 128 rows x 64 = 16 KB
#define BUF_US (A_US + B_US)   // 24576 ushorts = 48 KB per ring slot
#define NBUF 3                 // 144 KB LDS ring

typedef const __attribute__((address_space(1))) unsigned int gas_uint;
typedef __attribute__((address_space(3))) unsigned int las_uint;
#define ASYNC16(l, g) \
  __builtin_amdgcn_global_load_lds((gas_uint*)(g), (las_uint*)(l), 16, 0, 0)

#define LGKM0() do { \
  asm volatile("s_waitcnt lgkmcnt(0)" ::: "memory"); \
  __builtin_amdgcn_sched_barrier(0); \
} while (0)

__global__ __launch_bounds__(512, 2) void gemm_packed(
    const ushort_t* __restrict__ A,  // [BATCH][KP]
    const ushort_t* __restrict__ W,  // [OUT_F][KP]
    float* __restrict__ C) {         // [BATCH][OUT_F]
  __shared__ __align__(16) ushort_t lds[NBUF * BUF_US];  // 144 KB

  const int t = threadIdx.x;
  const int flat = blockIdx.x;           // 0..255
  const int xcd = flat & 7;
  const int local = flat >> 3;           // 0..31
  const int nt = local >> 2;             // 0..7
  const int mt = xcd * 4 + (local & 3);  // 0..31 (XCD-local A slabs)

  const int lane = t & 63;
  const int wave = t >> 6;  // 0..7
  const int wr = wave >> 1; // 0..3 (M)
  const int wc = wave & 1;  // 0..1 (N)
  const int lr = lane & 15;
  const int lq = lane >> 4;

  // staging: thread t -> LDS slot (row = t>>3, phys chunk = t&7); fetched
  // global k-chunk = phys ^ (row&7) (stays in the row's 128B segment).
  const int srow = t >> 3;               // 0..63
  const int kc = (t & 7) ^ (srow & 7);   // swizzled source k-chunk
  const ushort_t* ga = A + (size_t)(mt * BM + srow) * KP + kc * 8;
  const ushort_t* gb = W + (size_t)(nt * BN + srow) * KP + kc * 8;
  const int ldst = t * 8;                // ushort offset (t*16 B)
  const size_t rskip = (size_t)64 * KP;

  // fragment read offsets (read-side swizzle, ushorts)
  int aoff[2][4], boff[2][4];
#pragma unroll
  for (int kk = 0; kk < 2; ++kk)
#pragma unroll
    for (int i = 0; i < 4; ++i) {
      const int arow = wr * 64 + i * 16 + lr;
      const int brow = wc * 64 + i * 16 + lr;
      const int ks = kk * 4 + lq;
      aoff[kk][i] = arow * 64 + ((ks ^ (arow & 7)) << 3);
      boff[kk][i] = brow * 64 + ((ks ^ (brow & 7)) << 3);
    }

  f32x4 acc[4][4];
#pragma unroll
  for (int mi = 0; mi < 4; ++mi)
#pragma unroll
    for (int ni = 0; ni < 4; ++ni) acc[mi][ni] = (f32x4){0.f, 0.f, 0.f, 0.f};

  // prologue: tiles 0,1 fully in flight; wait tile 0 only
  {
    ushort_t* la = lds + ldst;
    ushort_t* lb = lds + A_US + ldst;
    ASYNC16(la, ga);              ASYNC16(la + 4096, ga + rskip);
    ASYNC16(la + 8192, ga + 2 * rskip); ASYNC16(la + 12288, ga + 3 * rskip);
    ASYNC16(lb, gb);              ASYNC16(lb + 4096, gb + rskip);
    la += BUF_US; lb += BUF_US;
    ASYNC16(la, ga + GBK);              ASYNC16(la + 4096, ga + GBK + rskip);
    ASYNC16(la + 8192, ga + GBK + 2 * rskip); ASYNC16(la + 12288, ga + GBK + 3 * rskip);
    ASYNC16(lb, gb + GBK);              ASYNC16(lb + 4096, gb + GBK + rskip);
  }
  asm volatile("s_waitcnt vmcnt(6)" ::: "memory");
  __builtin_amdgcn_s_barrier();
  __builtin_amdgcn_sched_barrier(0);

  // main loop: 4 phases/step; stage s+2 spread over P0..P2
  int co = 0;                 // compute ring offset (tile s)
  int so = 2 * BUF_US;        // stage ring offset (tile s+2)
  const ushort_t* gpa = ga + 2 * GBK;
  const ushort_t* gpb = gb + 2 * GBK;

#define MFMA8(KK, N0)                                                        \
  do {                                                                       \
    __builtin_amdgcn_s_setprio(1);                                           \
    _Pragma("unroll") for (int mi = 0; mi < 4; ++mi) {                       \
      acc[mi][N0] = __builtin_amdgcn_mfma_f32_16x16x32_bf16(                 \
          af##KK[mi], bf##KK[N0], acc[mi][N0], 0, 0, 0);                     \
      acc[mi][N0 + 1] = __builtin_amdgcn_mfma_f32_16x16x32_bf16(             \
          af##KK[mi], bf##KK[N0 + 1], acc[mi][N0 + 1], 0, 0, 0);             \
    }                                                                        \
    __builtin_amdgcn_s_setprio(0);                                           \
  } while (0)

#pragma unroll 3
  for (int s = 0; s < NSTEP - 2; ++s) {
    const ushort_t* ab = lds + co;
    const ushort_t* bb = lds + co + A_US;
    ushort_t* sa = lds + so + ldst;
    ushort_t* sb = lds + so + A_US + ldst;
    short8 af0[4], af1[4], bf0[4], bf1[4];

    // P0: reads af0 all, bf0[0..1] | stage A slabs 0,1
#pragma unroll
    for (int i = 0; i < 4; ++i) af0[i] = *(const short8*)(ab + aoff[0][i]);
    bf0[0] = *(const short8*)(bb + boff[0][0]);
    bf0[1] = *(const short8*)(bb + boff[0][1]);
    ASYNC16(sa, gpa);
    ASYNC16(sa + 4096, gpa + rskip);
    __builtin_amdgcn_s_barrier();
    LGKM0();
    MFMA8(0, 0);
    __builtin_amdgcn_s_barrier();

    // P1: reads bf0[2..3], af1[0..1] | stage A slabs 2,3
    bf0[2] = *(const short8*)(bb + boff[0][2]);
    bf0[3] = *(const short8*)(bb + boff[0][3]);
    af1[0] = *(const short8*)(ab + aoff[1][0]);
    af1[1] = *(const short8*)(ab + aoff[1][1]);
    ASYNC16(sa + 8192, gpa + 2 * rskip);
    ASYNC16(sa + 12288, gpa + 3 * rskip);
    __builtin_amdgcn_s_barrier();
    LGKM0();
    MFMA8(0, 2);
    __builtin_amdgcn_s_barrier();

    // P2: reads af1[2..3], bf1[0..1] | stage B slabs 0,1
    af1[2] = *(const short8*)(ab + aoff[1][2]);
    af1[3] = *(const short8*)(ab + aoff[1][3]);
    bf1[0] = *(const short8*)(bb + boff[1][0]);
    bf1[1] = *(const short8*)(bb + boff[1][1]);
    ASYNC16(sb, gpb);
    ASYNC16(sb + 4096, gpb + rskip);
    __builtin_amdgcn_s_barrier();
    LGKM0();
    MFMA8(1, 0);
    __builtin_amdgcn_s_barrier();

    // P3: reads bf1[2..3] | vmcnt(6): s+1 resident, s+2 in flight
    bf1[2] = *(const short8*)(bb + boff[1][2]);
    bf1[3] = *(const short8*)(bb + boff[1][3]);
    __builtin_amdgcn_s_barrier();
    LGKM0();
    MFMA8(1, 2);
    asm volatile("s_waitcnt vmcnt(6)" ::: "memory");
    __builtin_amdgcn_s_barrier();
    __builtin_amdgcn_sched_barrier(0);

    gpa += GBK;
    gpb += GBK;
    co += BUF_US; if (co == NBUF * BUF_US) co = 0;
    so += BUF_US; if (so == NBUF * BUF_US) so = 0;
  }

  // tail: two steps without staging
#pragma unroll 1
  for (int s = 0; s < 2; ++s) {
    const ushort_t* ab = lds + co;
    const ushort_t* bb = lds + co + A_US;
    short8 af0[4], af1[4], bf0[4], bf1[4];
#pragma unroll
    for (int i = 0; i < 4; ++i) af0[i] = *(const short8*)(ab + aoff[0][i]);
#pragma unroll
    for (int i = 0; i < 4; ++i) bf0[i] = *(const short8*)(bb + boff[0][i]);
#pragma unroll
    for (int i = 0; i < 4; ++i) af1[i] = *(const short8*)(ab + aoff[1][i]);
#pragma unroll
    for (int i = 0; i < 4; ++i) bf1[i] = *(const short8*)(bb + boff[1][i]);
    LGKM0();
    MFMA8(0, 0);
    MFMA8(0, 2);
    MFMA8(1, 0);
    MFMA8(1, 2);
    if (s == 0) {
      asm volatile("s_waitcnt vmcnt(0)" ::: "memory");
      __builtin_amdgcn_s_barrier();
      __builtin_amdgcn_sched_barrier(0);
      co += BUF_US; if (co == NBUF * BUF_US) co = 0;
    }
  }

  // epilogue: C/D layout col=lane&15, row=(lane>>4)*4+reg
  const int col0 = nt * BN + wc * 64 + lr;
  const int row0 = mt * BM + wr * 64 + (lq << 2);
#pragma unroll
  for (int mi = 0; mi < 4; ++mi)
#pragma unroll
    for (int ni = 0; ni < 4; ++ni) {
      float* cp = C + (size_t)(row0 + mi * 16) * OUT_F + col0 + ni * 16;
#pragma unroll
      for (int rr = 0; rr < 4; ++rr) cp[(size_t)rr * OUT_F] = acc[mi][ni][rr];
    }
}

extern "C" void kernel_launch(void* const* d_in, const int* in_sizes, int n_in,
                              void* d_out, int out_size, void* d_ws, size_t ws_size,
                              hipStream_t stream) {
  const float* x = (const float*)d_in[0];
  const float* wb = (const float*)d_in[1];
  const float* ws = (const float*)d_in[2];
  float* out = (float*)d_out;

  ushort_t* Apack = (ushort_t*)d_ws;                                    // 33.5 MB
  ushort_t* Wpack = (ushort_t*)((char*)d_ws + (size_t)BATCH * KP * 2);  // +4 MB

  prep_all<<<PREP_BLOCKS, 256, 0, stream>>>(x, wb, ws, Apack, Wpack);
  gemm_packed<<<dim3((BATCH / BM) * (OUT_F / BN)), dim3(512), 0, stream>>>(Apack, Wpack, out);
}